// Round 2
// baseline (469.629 us; speedup 1.0000x reference)
//
#include <hip/hip_runtime.h>
#include <hip/hip_bf16.h>
#include <stdint.h>

// Problem constants (N=8192 rows, C=4096 classes; reduction dim of joint GEMM = N)
#define NROWS 8192
#define CDIM  4096
#define KDIM  8192
#define EPS   1e-12f

typedef __attribute__((ext_vector_type(8)))  int   v8i;     // 32 fp8 bytes (8 VGPRs)
typedef __attribute__((ext_vector_type(4)))  int   v4i;     // 16 fp8 bytes (4 VGPRs)
typedef __attribute__((ext_vector_type(4)))  float f32x4;
typedef __attribute__((ext_vector_type(2)))  float f32x2;

// Butterfly reductions: all lanes end with the result.
__device__ inline float wave_sum(float v) {
#pragma unroll
    for (int o = 32; o > 0; o >>= 1) v += __shfl_xor(v, o, 64);
    return v;
}
__device__ inline float wave_max(float v) {
#pragma unroll
    for (int o = 32; o > 0; o >>= 1) v = fmaxf(v, __shfl_xor(v, o, 64));
    return v;
}

// ---------------------------------------------------------------------------
// Pass 1: wave-per-row softmax stats + entropy + fp8 quantized row-major write.
// Row (4096 f32 = 16 KB) lives in 64 VGPRs/lane; butterfly reductions; the
// normalized probs are quantized fp8(512*p) and stored [N][C] with coalesced
// dword stores. No stats arrays, no second f32 read, no exp recompute.
// entropy_n = max + lnZ - (sum e^{x-max} * x)/Z. grid=(2048,2): y=1 -> Y.
// ---------------------------------------------------------------------------
__global__ __launch_bounds__(256) void row_quant_kernel(const float* __restrict__ X,
                                                        const float* __restrict__ Y,
                                                        unsigned char* __restrict__ QX,
                                                        unsigned char* __restrict__ QY,
                                                        float* __restrict__ entPart) {
    const int t = threadIdx.x, lane = t & 63, wave = t >> 6;
    const int row = blockIdx.x * 4 + wave;
    const bool isY = blockIdx.y != 0;
    const float4* s4 = (const float4*)((isY ? Y : X) + (size_t)row * CDIM);
    unsigned int* dst = (unsigned int*)((isY ? QY : QX) + (size_t)row * CDIM);
    float4 v[16];
#pragma unroll
    for (int i = 0; i < 16; i++) v[i] = s4[i * 64 + lane];
    float m = -3.0e38f;
#pragma unroll
    for (int i = 0; i < 16; i++)
        m = fmaxf(m, fmaxf(fmaxf(v[i].x, v[i].y), fmaxf(v[i].z, v[i].w)));
    m = wave_max(m);
    float Z = 0.f, S = 0.f;
#pragma unroll
    for (int i = 0; i < 16; i++) {
        float e;
        e = __expf(v[i].x - m); Z += e; S += e * v[i].x; v[i].x = e;
        e = __expf(v[i].y - m); Z += e; S += e * v[i].y; v[i].y = e;
        e = __expf(v[i].z - m); Z += e; S += e * v[i].z; v[i].z = e;
        e = __expf(v[i].w - m); Z += e; S += e * v[i].w; v[i].w = e;
    }
    Z = wave_sum(Z); S = wave_sum(S);
    __shared__ float sent[4];
    if (lane == 0) sent[wave] = m + __logf(Z) - S / Z;
    // quantize: q = fp8(512 * e / Z). 512*p_max ~ 4 << 448 (e4m3 max) -> safe.
    const float sc = 512.0f / Z;
#pragma unroll
    for (int i = 0; i < 16; i++) {
        unsigned int w0 = (unsigned int)__builtin_amdgcn_cvt_pk_fp8_f32(
            v[i].x * sc, v[i].y * sc, 0, false);
        w0 = (unsigned int)__builtin_amdgcn_cvt_pk_fp8_f32(
            v[i].z * sc, v[i].w * sc, (int)w0, true);
        dst[i * 64 + lane] = w0;   // 64 lanes x 4B contiguous = 256B/instr
    }
    __syncthreads();
    if (t == 0 && !isY)
        entPart[blockIdx.x] = sent[0] + sent[1] + sent[2] + sent[3];
}

// ---------------------------------------------------------------------------
// Pass 2: fp8 [N][C] -> [C][N] transpose, 128x128 byte tiles. v_perm 4x4 byte
// micro-transpose in registers, then an XOR-swizzled LDS tile so the global
// write-out is COALESCED (R2 change).
//
// R1 version wrote 16B uint4 per thread at 32KB-apart addresses: 64 scattered
// 16B stores per wave = 4x HBM write amplification (64B granule) -> ~200us.
// R2: micro-transposed 16B chunks go to LDS[row][unit ^ ((row>>2)&7)]; after a
// barrier, lanes 0..7 read one row's 8 units (unswizzled) and store one
// contiguous 128B row chunk: zero write amplification.
// Bank check (both sides): every consecutive-8-lane group covers all 8
// 16B-units = all 32 banks (write: unit = (t>>5)^(l&7) spread; read: k=t&7
// XOR row-const), 2 lanes/bank max = free (m136).
// Margins (sum over n of dequantized fp8, per class) fused as before.
// grid = (32, 64, 2): x=c-tile, y=n-tile, z selects X/Y.
// ---------------------------------------------------------------------------
__global__ __launch_bounds__(256) void transpose_marg_kernel(
        const unsigned char* __restrict__ QX, const unsigned char* __restrict__ QY,
        unsigned char* __restrict__ QXT, unsigned char* __restrict__ QYT,
        float* __restrict__ margX, float* __restrict__ margY) {
    const bool isY = blockIdx.z != 0;
    const unsigned char* __restrict__ Q = isY ? QY : QX;
    unsigned char* __restrict__ QT = isY ? QYT : QXT;
    float* __restrict__ marg = isY ? margY : margX;

    __shared__ __align__(16) unsigned char tile[128 * 128];   // 16 KB transposed tile
    __shared__ float smarg[128];
    const int t = threadIdx.x;
    const int c0 = blockIdx.x * 128, n0 = blockIdx.y * 128;
    if (t < 128) smarg[t] = 0.f;
    __syncthreads();
    const int cq = (t & 31) * 4;   // class offset within tile (x4)
    const int nq = (t >> 5) * 16;  // n offset within tile (x16)
    const unsigned char* src = Q + (size_t)(n0 + nq) * CDIM + c0 + cq;
    unsigned int u[16];
#pragma unroll
    for (int i = 0; i < 16; i++)
        u[i] = *(const unsigned int*)(src + (size_t)i * CDIM);  // 2 rows x 128B per instr
    // 4x4 byte micro-transpose: d[j][k] = n-consecutive bytes for class cq+j
#pragma unroll
    for (int j = 0; j < 4; j++) {
        const unsigned int sel = (unsigned)j | ((unsigned)(j + 4) << 8);
        unsigned int d0, d1, d2, d3;
        {
            unsigned int p01 = __builtin_amdgcn_perm(u[1], u[0], sel);
            unsigned int p23 = __builtin_amdgcn_perm(u[3], u[2], sel);
            d0 = __builtin_amdgcn_perm(p23, p01, 0x05040100u);
        }
        {
            unsigned int p01 = __builtin_amdgcn_perm(u[5], u[4], sel);
            unsigned int p23 = __builtin_amdgcn_perm(u[7], u[6], sel);
            d1 = __builtin_amdgcn_perm(p23, p01, 0x05040100u);
        }
        {
            unsigned int p01 = __builtin_amdgcn_perm(u[9], u[8], sel);
            unsigned int p23 = __builtin_amdgcn_perm(u[11], u[10], sel);
            d2 = __builtin_amdgcn_perm(p23, p01, 0x05040100u);
        }
        {
            unsigned int p01 = __builtin_amdgcn_perm(u[13], u[12], sel);
            unsigned int p23 = __builtin_amdgcn_perm(u[15], u[14], sel);
            d3 = __builtin_amdgcn_perm(p23, p01, 0x05040100u);
        }
        const int r = cq + j;                        // out-row within tile
        // swizzled LDS write: logical unit nq>>4, physical unit ^ ((r>>2)&7)
        uint4 o; o.x = d0; o.y = d1; o.z = d2; o.w = d3;
        *(uint4*)&tile[r * 128 + ((((nq >> 4) ^ ((r >> 2) & 7))) << 4)] = o;
        // margin partial: dequant-sum the 16 fp8 values (same bytes GEMM reads)
        float s = 0.f;
        f32x2 a;
        a = __builtin_amdgcn_cvt_pk_f32_fp8((int)d0, false); s += a.x + a.y;
        a = __builtin_amdgcn_cvt_pk_f32_fp8((int)d0, true);  s += a.x + a.y;
        a = __builtin_amdgcn_cvt_pk_f32_fp8((int)d1, false); s += a.x + a.y;
        a = __builtin_amdgcn_cvt_pk_f32_fp8((int)d1, true);  s += a.x + a.y;
        a = __builtin_amdgcn_cvt_pk_f32_fp8((int)d2, false); s += a.x + a.y;
        a = __builtin_amdgcn_cvt_pk_f32_fp8((int)d2, true);  s += a.x + a.y;
        a = __builtin_amdgcn_cvt_pk_f32_fp8((int)d3, false); s += a.x + a.y;
        a = __builtin_amdgcn_cvt_pk_f32_fp8((int)d3, true);  s += a.x + a.y;
        atomicAdd(&smarg[r], s);
    }
    __syncthreads();
    // coalesced write-out: 4 rounds; lanes 0..7 emit one contiguous 128B row
#pragma unroll
    for (int p = 0; p < 4; p++) {
        const int r = p * 32 + (t >> 3);             // out-row within tile
        const int k = t & 7;                         // logical 16B unit
        uint4 o = *(const uint4*)&tile[r * 128 + (((k ^ ((r >> 2) & 7))) << 4)];
        *(uint4*)(QT + (size_t)(c0 + r) * KDIM + n0 + k * 16) = o;
    }
    if (t < 128) atomicAdd(&marg[c0 + t], smarg[t]);
}

// ---------------------------------------------------------------------------
// Pass 3: joint GEMM, MX-fp8 16x16x128 (m148 pattern: BK=128, 16 MFMA + 8
// GLD16 per barrier-pair), fused epilogue sum j*log(j+eps). Global-sum
// epilogue + identical A/B fragment rule -> layout/K-order errors cancel.
// R1: XOR-swizzled LDS (T2 both-sides form) — conflicts 5.0e7 -> 1.7e7,
// MfmaUtil 32 -> 36.6%. Now at the m97-structure ceiling; unchanged in R2.
// ---------------------------------------------------------------------------
#define GLD16(g, l)                                                                   \
    __builtin_amdgcn_global_load_lds((const __attribute__((address_space(1))) unsigned int*)(g), \
                                     (__attribute__((address_space(3))) unsigned int*)(l), 16, 0, 0)

__global__ __launch_bounds__(256) void gemm_mi_kernel(const unsigned char* __restrict__ A,
                                                      const unsigned char* __restrict__ B,
                                                      float* __restrict__ S_out) {
    __shared__ __align__(16) unsigned char As[128 * 128];   // 16 KB: 128 rows x 128B (BK=128)
    __shared__ __align__(16) unsigned char Bs[128 * 128];
    const int t = threadIdx.x;
    const int m0 = blockIdx.x * 128, n0 = blockIdx.y * 128;
    // staging: 4 GLD16 per matrix per thread; instr i of wave w fills LDS
    // rows [w*32+i*8, +8) x 128B contiguously in lane order (global_load_lds rule)
    const int grow = (t >> 6) * 32 + ((t & 63) >> 3);   // row this lane sources
    // pre-swizzled global source unit: (l&7) ^ (l>>3)  (l>>3 == row&7)
    const int gcol = (((t & 7) ^ ((t & 63) >> 3)) * 16);
    const unsigned char* ga = A + (size_t)(m0 + grow) * KDIM + gcol;
    const unsigned char* gb = B + (size_t)(n0 + grow) * KDIM + gcol;
    unsigned char* la = &As[(t >> 6) * 4096 + (t & 63) * 16];
    unsigned char* lb = &Bs[(t >> 6) * 4096 + (t & 63) * 16];
    const int lane = t & 63, wave = t >> 6;
    const int wm = (wave & 1) * 64, wn = (wave >> 1) * 64;   // wave tile 64x64
    const int fr = lane & 15, quad = lane >> 4;
    // fragment rule (same for A and B): row = tile+fr, k bytes quad*32..+31,
    // fetched from swizzled physical units (2q)^(fr&7) and (2q+1)^(fr&7).
    const int sw = fr & 7;
    const int off0 = ((2 * quad)     ^ sw) * 16;
    const int off1 = ((2 * quad + 1) ^ sw) * 16;
    const unsigned char* pA = &As[(wm + fr) * 128];
    const unsigned char* pB = &Bs[(wn + fr) * 128];
    f32x4 acc[4][4];
#pragma unroll
    for (int i = 0; i < 4; i++)
#pragma unroll
        for (int j = 0; j < 4; j++) { acc[i][j][0] = 0.f; acc[i][j][1] = 0.f; acc[i][j][2] = 0.f; acc[i][j][3] = 0.f; }

    for (int k0 = 0; k0 < KDIM; k0 += 128) {
#pragma unroll
        for (int i = 0; i < 4; i++) {
            GLD16(ga + (size_t)i * 8 * KDIM + k0, la + i * 1024);
            GLD16(gb + (size_t)i * 8 * KDIM + k0, lb + i * 1024);
        }
        __syncthreads();   // drains vmcnt before barrier (m97 semantics)
        v8i af[4], bg[4];
#pragma unroll
        for (int i = 0; i < 4; i++) {
            v4i lo = *(const v4i*)(pA + i * 16 * 128 + off0);
            v4i hi = *(const v4i*)(pA + i * 16 * 128 + off1);
            af[i][0] = lo[0]; af[i][1] = lo[1]; af[i][2] = lo[2]; af[i][3] = lo[3];
            af[i][4] = hi[0]; af[i][5] = hi[1]; af[i][6] = hi[2]; af[i][7] = hi[3];
        }
#pragma unroll
        for (int j = 0; j < 4; j++) {
            v4i lo = *(const v4i*)(pB + j * 16 * 128 + off0);
            v4i hi = *(const v4i*)(pB + j * 16 * 128 + off1);
            bg[j][0] = lo[0]; bg[j][1] = lo[1]; bg[j][2] = lo[2]; bg[j][3] = lo[3];
            bg[j][4] = hi[0]; bg[j][5] = hi[1]; bg[j][6] = hi[2]; bg[j][7] = hi[3];
        }
#pragma unroll
        for (int i = 0; i < 4; i++)
#pragma unroll
            for (int j = 0; j < 4; j++)
                acc[i][j] = __builtin_amdgcn_mfma_scale_f32_16x16x128_f8f6f4(
                    af[i], bg[j], acc[i][j], 0 /*A=fp8*/, 0 /*B=fp8*/,
                    0, 0x7f /*scaleA e8m0=1.0*/, 0, 0x7f /*scaleB*/);
        __syncthreads();
    }
    // epilogue: acc = 512^2 * N * joint -> joint = acc * 2^-31. Global sum.
    const float invS = 4.656612873077393e-10f;   // 2^-31
    float loc = 0.f;
#pragma unroll
    for (int i = 0; i < 4; i++)
#pragma unroll
        for (int j = 0; j < 4; j++)
#pragma unroll
            for (int r = 0; r < 4; r++) {
                float v = acc[i][j][r] * invS;
                loc += v * __logf(v + EPS);
            }
    loc = wave_sum(loc);
    __shared__ float sred[4];
    if (lane == 0) sred[wave] = loc;
    __syncthreads();
    if (t == 0) atomicAdd(S_out, sred[0] + sred[1] + sred[2] + sred[3]);
}

// ---------------------------------------------------------------------------
// Pass 4: finalize. entropy = sum entPart / N;
// MI = S_jlogj - sum mX log(mX+eps) - sum mY log(mY+eps); marg scale 2^-22.
// ---------------------------------------------------------------------------
__global__ __launch_bounds__(256) void finalize_kernel(const float* __restrict__ accums,
                                                       const float* __restrict__ entPart,
                                                       const float* __restrict__ margX,
                                                       const float* __restrict__ margY,
                                                       float* __restrict__ out) {
    const int t = threadIdx.x;
    const int lane = t & 63, w = t >> 6;
    const float invN = 1.0f / 8192.0f;
    const float invM = 1.0f / 4194304.0f;   // 1/(512*8192) = 2^-22
    float sx = 0.f, sy = 0.f, se = 0.f;
    for (int c = t; c < CDIM; c += 256) {
        float mx = margX[c] * invM;
        float my = margY[c] * invM;
        sx += mx * __logf(mx + EPS);
        sy += my * __logf(my + EPS);
    }
    for (int c = t; c < 2048; c += 256) se += entPart[c];
    sx = wave_sum(sx); sy = wave_sum(sy); se = wave_sum(se);
    __shared__ float rx[4], ry[4], re[4];
    if (lane == 0) { rx[w] = sx; ry[w] = sy; re[w] = se; }
    __syncthreads();
    if (t == 0) {
        float SX = rx[0] + rx[1] + rx[2] + rx[3];
        float SY = ry[0] + ry[1] + ry[2] + ry[3];
        float SE = re[0] + re[1] + re[2] + re[3];
        out[0] = SE * invN;                 // mean entropy
        out[1] = accums[0] - SX - SY;       // MI
    }
}

// ---------------------------------------------------------------------------
// Workspace layout (bytes):
//   0          QX   fp8 [8192][4096]   33554432   (row-major probs x512)
//   33554432   QY   fp8 [8192][4096]   33554432
//   67108864   QXT  fp8 [4096][8192]   33554432   (transposed, GEMM operand)
//   100663296  QYT  fp8 [4096][8192]   33554432
//   134217728  margX f32[4096]            16384
//   134234112  margY f32[4096]            16384
//   134250496  accums f32[0]=S_jlogj        256
//   134250752  entPart f32[2048]           8192
// ---------------------------------------------------------------------------
extern "C" void kernel_launch(void* const* d_in, const int* in_sizes, int n_in,
                              void* d_out, int out_size, void* d_ws, size_t ws_size,
                              hipStream_t stream) {
    const float* X = (const float*)d_in[0];
    const float* Y = (const float*)d_in[1];
    char* ws = (char*)d_ws;
    unsigned char* QX  = (unsigned char*)ws;
    unsigned char* QY  = (unsigned char*)(ws + 33554432ll);
    unsigned char* QXT = (unsigned char*)(ws + 67108864ll);
    unsigned char* QYT = (unsigned char*)(ws + 100663296ll);
    float* margX = (float*)(ws + 134217728ll);
    float* margY = (float*)(ws + 134234112ll);
    float* accums = (float*)(ws + 134250496ll);
    float* entPart = (float*)(ws + 134250752ll);

    // zero margins + accumulators (ws is poisoned 0xAA before every launch)
    hipMemsetAsync(ws + 134217728ll, 0, 2 * 16384 + 256, stream);

    row_quant_kernel<<<dim3(2048, 2), 256, 0, stream>>>(X, Y, QX, QY, entPart);
    transpose_marg_kernel<<<dim3(CDIM / 128, NROWS / 128, 2), 256, 0, stream>>>(
        QX, QY, QXT, QYT, margX, margY);
    gemm_mi_kernel<<<dim3(CDIM / 128, CDIM / 128), 256, 0, stream>>>(QXT, QYT, &accums[0]);
    finalize_kernel<<<1, 256, 0, stream>>>(accums, entPart, margX, margY, (float*)d_out);
}

// Round 4
// 457.324 us; speedup vs baseline: 1.0269x; 1.0269x over previous
//
#include <hip/hip_runtime.h>
#include <hip/hip_bf16.h>
#include <stdint.h>

// Problem constants (N=8192 rows, C=4096 classes; reduction dim of joint GEMM = N)
#define NROWS 8192
#define CDIM  4096
#define KDIM  8192
#define EPS   1e-12f

typedef __attribute__((ext_vector_type(8)))  int   v8i;     // 32 fp8 bytes (8 VGPRs)
typedef __attribute__((ext_vector_type(4)))  int   v4i;     // 16 fp8 bytes (4 VGPRs)
typedef __attribute__((ext_vector_type(4)))  float f32x4;
typedef __attribute__((ext_vector_type(2)))  float f32x2;

// Butterfly reductions: all lanes end with the result.
__device__ inline float wave_sum(float v) {
#pragma unroll
    for (int o = 32; o > 0; o >>= 1) v += __shfl_xor(v, o, 64);
    return v;
}
__device__ inline float wave_max(float v) {
#pragma unroll
    for (int o = 32; o > 0; o >>= 1) v = fmaxf(v, __shfl_xor(v, o, 64));
    return v;
}

// ---------------------------------------------------------------------------
// Pass 1: wave-per-row softmax stats + entropy + fp8 quantized row-major write.
// Row (4096 f32 = 16 KB) lives in 64 VGPRs/lane; butterfly reductions; the
// normalized probs are quantized fp8(512*p) and stored [N][C] with coalesced
// dword stores. entropy_n = max + lnZ - (sum e^{x-max} * x)/Z.
// grid=(2048,2): y=1 -> Y.
// ---------------------------------------------------------------------------
__global__ __launch_bounds__(256) void row_quant_kernel(const float* __restrict__ X,
                                                        const float* __restrict__ Y,
                                                        unsigned char* __restrict__ QX,
                                                        unsigned char* __restrict__ QY,
                                                        float* __restrict__ entPart) {
    const int t = threadIdx.x, lane = t & 63, wave = t >> 6;
    const int row = blockIdx.x * 4 + wave;
    const bool isY = blockIdx.y != 0;
    const float4* s4 = (const float4*)((isY ? Y : X) + (size_t)row * CDIM);
    unsigned int* dst = (unsigned int*)((isY ? QY : QX) + (size_t)row * CDIM);
    float4 v[16];
#pragma unroll
    for (int i = 0; i < 16; i++) v[i] = s4[i * 64 + lane];
    float m = -3.0e38f;
#pragma unroll
    for (int i = 0; i < 16; i++)
        m = fmaxf(m, fmaxf(fmaxf(v[i].x, v[i].y), fmaxf(v[i].z, v[i].w)));
    m = wave_max(m);
    float Z = 0.f, S = 0.f;
#pragma unroll
    for (int i = 0; i < 16; i++) {
        float e;
        e = __expf(v[i].x - m); Z += e; S += e * v[i].x; v[i].x = e;
        e = __expf(v[i].y - m); Z += e; S += e * v[i].y; v[i].y = e;
        e = __expf(v[i].z - m); Z += e; S += e * v[i].z; v[i].z = e;
        e = __expf(v[i].w - m); Z += e; S += e * v[i].w; v[i].w = e;
    }
    Z = wave_sum(Z); S = wave_sum(S);
    __shared__ float sent[4];
    if (lane == 0) sent[wave] = m + __logf(Z) - S / Z;
    // quantize: q = fp8(512 * e / Z). 512*p_max ~ 4 << 448 (e4m3 max) -> safe.
    const float sc = 512.0f / Z;
#pragma unroll
    for (int i = 0; i < 16; i++) {
        unsigned int w0 = (unsigned int)__builtin_amdgcn_cvt_pk_fp8_f32(
            v[i].x * sc, v[i].y * sc, 0, false);
        w0 = (unsigned int)__builtin_amdgcn_cvt_pk_fp8_f32(
            v[i].z * sc, v[i].w * sc, (int)w0, true);
        dst[i * 64 + lane] = w0;   // 64 lanes x 4B contiguous = 256B/instr
    }
    __syncthreads();
    if (t == 0 && !isY)
        entPart[blockIdx.x] = sent[0] + sent[1] + sent[2] + sent[3];
}

// ---------------------------------------------------------------------------
// Pass 2: fp8 [N][C] -> [C][N] transpose, 128x128 byte tiles. v_perm 4x4 byte
// micro-transpose in registers, then an XOR-swizzled LDS tile so the global
// write-out is coalesced. (R2; R1's scattered stores were L2/L3-absorbed, so
// this was neutral — kept because it is not worse and the write path is clean.)
// Margins (sum over n of dequantized fp8, per class) fused.
// grid = (32, 64, 2): x=c-tile, y=n-tile, z selects X/Y.
// ---------------------------------------------------------------------------
__global__ __launch_bounds__(256) void transpose_marg_kernel(
        const unsigned char* __restrict__ QX, const unsigned char* __restrict__ QY,
        unsigned char* __restrict__ QXT, unsigned char* __restrict__ QYT,
        float* __restrict__ margX, float* __restrict__ margY) {
    const bool isY = blockIdx.z != 0;
    const unsigned char* __restrict__ Q = isY ? QY : QX;
    unsigned char* __restrict__ QT = isY ? QYT : QXT;
    float* __restrict__ marg = isY ? margY : margX;

    __shared__ __align__(16) unsigned char tile[128 * 128];   // 16 KB transposed tile
    __shared__ float smarg[128];
    const int t = threadIdx.x;
    const int c0 = blockIdx.x * 128, n0 = blockIdx.y * 128;
    if (t < 128) smarg[t] = 0.f;
    __syncthreads();
    const int cq = (t & 31) * 4;   // class offset within tile (x4)
    const int nq = (t >> 5) * 16;  // n offset within tile (x16)
    const unsigned char* src = Q + (size_t)(n0 + nq) * CDIM + c0 + cq;
    unsigned int u[16];
#pragma unroll
    for (int i = 0; i < 16; i++)
        u[i] = *(const unsigned int*)(src + (size_t)i * CDIM);  // 2 rows x 128B per instr
    // 4x4 byte micro-transpose: d[j][k] = n-consecutive bytes for class cq+j
#pragma unroll
    for (int j = 0; j < 4; j++) {
        const unsigned int sel = (unsigned)j | ((unsigned)(j + 4) << 8);
        unsigned int d0, d1, d2, d3;
        {
            unsigned int p01 = __builtin_amdgcn_perm(u[1], u[0], sel);
            unsigned int p23 = __builtin_amdgcn_perm(u[3], u[2], sel);
            d0 = __builtin_amdgcn_perm(p23, p01, 0x05040100u);
        }
        {
            unsigned int p01 = __builtin_amdgcn_perm(u[5], u[4], sel);
            unsigned int p23 = __builtin_amdgcn_perm(u[7], u[6], sel);
            d1 = __builtin_amdgcn_perm(p23, p01, 0x05040100u);
        }
        {
            unsigned int p01 = __builtin_amdgcn_perm(u[9], u[8], sel);
            unsigned int p23 = __builtin_amdgcn_perm(u[11], u[10], sel);
            d2 = __builtin_amdgcn_perm(p23, p01, 0x05040100u);
        }
        {
            unsigned int p01 = __builtin_amdgcn_perm(u[13], u[12], sel);
            unsigned int p23 = __builtin_amdgcn_perm(u[15], u[14], sel);
            d3 = __builtin_amdgcn_perm(p23, p01, 0x05040100u);
        }
        const int r = cq + j;                        // out-row within tile
        // swizzled LDS write: logical unit nq>>4, physical unit ^ ((r>>2)&7)
        uint4 o; o.x = d0; o.y = d1; o.z = d2; o.w = d3;
        *(uint4*)&tile[r * 128 + ((((nq >> 4) ^ ((r >> 2) & 7))) << 4)] = o;
        // margin partial: dequant-sum the 16 fp8 values (same bytes GEMM reads)
        float s = 0.f;
        f32x2 a;
        a = __builtin_amdgcn_cvt_pk_f32_fp8((int)d0, false); s += a.x + a.y;
        a = __builtin_amdgcn_cvt_pk_f32_fp8((int)d0, true);  s += a.x + a.y;
        a = __builtin_amdgcn_cvt_pk_f32_fp8((int)d1, false); s += a.x + a.y;
        a = __builtin_amdgcn_cvt_pk_f32_fp8((int)d1, true);  s += a.x + a.y;
        a = __builtin_amdgcn_cvt_pk_f32_fp8((int)d2, false); s += a.x + a.y;
        a = __builtin_amdgcn_cvt_pk_f32_fp8((int)d2, true);  s += a.x + a.y;
        a = __builtin_amdgcn_cvt_pk_f32_fp8((int)d3, false); s += a.x + a.y;
        a = __builtin_amdgcn_cvt_pk_f32_fp8((int)d3, true);  s += a.x + a.y;
        atomicAdd(&smarg[r], s);
    }
    __syncthreads();
    // coalesced write-out: 4 rounds; lanes 0..7 emit one contiguous 128B row
#pragma unroll
    for (int p = 0; p < 4; p++) {
        const int r = p * 32 + (t >> 3);             // out-row within tile
        const int k = t & 7;                         // logical 16B unit
        uint4 o = *(const uint4*)&tile[r * 128 + (((k ^ ((r >> 2) & 7))) << 4)];
        *(uint4*)(QT + (size_t)(c0 + r) * KDIM + n0 + k * 16) = o;
    }
    if (t < 128) atomicAdd(&marg[c0 + t], smarg[t]);
}

// ---------------------------------------------------------------------------
// Pass 3 (R3 structure, R4 resubmit with sched_barrier pins): joint GEMM,
// MX-fp8 16x16x128, 256x256 tile, BK=128, 8 waves (2x4), wave-tile 128x64
// (acc 8x4), double-buffered 128 KB LDS, prefetch-next-tile with COUNTED
// vmcnt(8) across raw s_barrier (T3+T4; never drain-0 in the loop),
// lgkmcnt(0) before the end-of-tile barrier (closes buffer-overwrite race),
// T5 setprio around the MFMA cluster. Fragment rule identical for A and B and
// epilogue is a global permutation-invariant sum -> layout errors cancel;
// per-entry MFMA K-order identical to R2 -> bit-identical result.
//
// Why: the 128² 2-barrier structure measured MfmaUtil 36.6% (m97-ceiling
// signature); dbuf/vmcnt grafts on that structure are proven null (m99-m131);
// the 256² pipelined template is the proven fix (m201 regime gate).
// Per-CU floors here: MFMA 59 us, LDS frag-reads 61 us (ratio 0.375/MFMA at
// 8x4), VMEM ~1.05 GB logical — overlapped by the pipeline.
// sched_barrier(0) after each s_barrier pins VMEM-issue/ds_read/MFMA on the
// correct side of the sync points (rule #18 mechanism: "memory" clobbers do
// not order register-only MFMA; sched_barrier(0) does).
// ---------------------------------------------------------------------------
#define GLD16(g, l)                                                                   \
    __builtin_amdgcn_global_load_lds((const __attribute__((address_space(1))) unsigned int*)(g), \
                                     (__attribute__((address_space(3))) unsigned int*)(l), 16, 0, 0)

#define BUFSZ 65536   // one (A 32K + B 32K) tile pair
#define BOFS  32768   // B region offset within a buffer

__global__ __launch_bounds__(512, 2) void gemm_mi_kernel(const unsigned char* __restrict__ A,
                                                         const unsigned char* __restrict__ B,
                                                         float* __restrict__ S_out) {
    __shared__ __align__(16) unsigned char lds[131072];   // 2 x (32K A + 32K B)
    const int t = threadIdx.x;
    const int lane = t & 63, wave = t >> 6;
    const int m0 = blockIdx.x * 256, n0 = blockIdx.y * 256;

    // --- staging map: 4 GLD16 per matrix per thread per K-tile ---
    // wave w instr i fills rows [w*32 + i*8, +8) x 128B linearly in lane order.
    const int srow = wave * 32 + (lane >> 3);             // row this lane sources
    // pre-swizzled global source unit: (l&7) ^ (l>>3)   (l>>3 == row&7)
    const int gcol = ((lane & 7) ^ (lane >> 3)) * 16;
    const unsigned char* ga = A + (size_t)(m0 + srow) * KDIM + gcol;
    const unsigned char* gb = B + (size_t)(n0 + srow) * KDIM + gcol;
    const int loff = wave * 4096 + lane * 16;             // linear LDS dest

    // --- fragment map: wave-tile 128x64 at (wm, wn); rows wm+i*16+fr ---
    const int wm = (wave >> 2) * 128, wn = (wave & 3) * 64;
    const int fr = lane & 15, quad = lane >> 4, sw = fr & 7;
    // logical 32B K-chunk (2q,2q+1) lives at physical units ^(row&7); row&7==fr&7
    const int off0 = ((2 * quad)     ^ sw) * 16;
    const int off1 = ((2 * quad + 1) ^ sw) * 16;

    f32x4 acc[8][4];
#pragma unroll
    for (int i = 0; i < 8; i++)
#pragma unroll
        for (int j = 0; j < 4; j++) { acc[i][j][0] = 0.f; acc[i][j][1] = 0.f; acc[i][j][2] = 0.f; acc[i][j][3] = 0.f; }

    // prologue: stage tile 0 into buffer 0
#pragma unroll
    for (int i = 0; i < 4; i++) {
        GLD16(ga + (size_t)i * 8 * KDIM, lds + loff + i * 1024);
        GLD16(gb + (size_t)i * 8 * KDIM, lds + BOFS + loff + i * 1024);
    }

    int cur = 0;
    for (int tt = 0; tt < KDIM / 128; ++tt) {
        if (tt + 1 < KDIM / 128) {
            const int nb = (cur ^ 1) * BUFSZ;
            const int kn = (tt + 1) * 128;
#pragma unroll
            for (int i = 0; i < 4; i++) {
                GLD16(ga + (size_t)i * 8 * KDIM + kn, lds + nb + loff + i * 1024);
                GLD16(gb + (size_t)i * 8 * KDIM + kn, lds + nb + BOFS + loff + i * 1024);
            }
            // wait only the CURRENT tile's 8 loads; next tile's 8 stay in flight
            asm volatile("s_waitcnt vmcnt(8)" ::: "memory");
        } else {
            asm volatile("s_waitcnt vmcnt(0)" ::: "memory");
        }
        asm volatile("s_barrier" ::: "memory");           // tile tt ready for all waves
        __builtin_amdgcn_sched_barrier(0);

        const unsigned char* base = lds + cur * BUFSZ;
        v8i bg[4];
#pragma unroll
        for (int j = 0; j < 4; j++) {
            const unsigned char* pB = base + BOFS + (wn + j * 16 + fr) * 128;
            v4i lo = *(const v4i*)(pB + off0);
            v4i hi = *(const v4i*)(pB + off1);
            bg[j][0] = lo[0]; bg[j][1] = lo[1]; bg[j][2] = lo[2]; bg[j][3] = lo[3];
            bg[j][4] = hi[0]; bg[j][5] = hi[1]; bg[j][6] = hi[2]; bg[j][7] = hi[3];
        }
        __builtin_amdgcn_s_setprio(1);
#pragma unroll
        for (int i = 0; i < 8; i++) {
            const unsigned char* pA = base + (wm + i * 16 + fr) * 128;
            v4i lo = *(const v4i*)(pA + off0);
            v4i hi = *(const v4i*)(pA + off1);
            v8i af;
            af[0] = lo[0]; af[1] = lo[1]; af[2] = lo[2]; af[3] = lo[3];
            af[4] = hi[0]; af[5] = hi[1]; af[6] = hi[2]; af[7] = hi[3];
#pragma unroll
            for (int j = 0; j < 4; j++)
                acc[i][j] = __builtin_amdgcn_mfma_scale_f32_16x16x128_f8f6f4(
                    af, bg[j], acc[i][j], 0 /*A=fp8*/, 0 /*B=fp8*/,
                    0, 0x7f /*scaleA e8m0=1.0*/, 0, 0x7f /*scaleB*/);
        }
        __builtin_amdgcn_s_setprio(0);
        __builtin_amdgcn_sched_barrier(0);
        // drain my LDS reads, then barrier: after this, others may overwrite cur
        asm volatile("s_waitcnt lgkmcnt(0)" ::: "memory");
        asm volatile("s_barrier" ::: "memory");
        __builtin_amdgcn_sched_barrier(0);
        cur ^= 1;
    }

    // epilogue: acc = 512^2 * N * joint -> joint = acc * 2^-31. Global sum.
    const float invS = 4.656612873077393e-10f;   // 2^-31
    float loc = 0.f;
#pragma unroll
    for (int i = 0; i < 8; i++)
#pragma unroll
        for (int j = 0; j < 4; j++)
#pragma unroll
            for (int r = 0; r < 4; r++) {
                float v = acc[i][j][r] * invS;
                loc += v * __logf(v + EPS);
            }
    loc = wave_sum(loc);
    __shared__ float sred[8];
    if (lane == 0) sred[wave] = loc;
    __syncthreads();
    if (t == 0) {
        float s = 0.f;
#pragma unroll
        for (int w = 0; w < 8; w++) s += sred[w];
        atomicAdd(S_out, s);
    }
}

// ---------------------------------------------------------------------------
// Pass 4: finalize. entropy = sum entPart / N;
// MI = S_jlogj - sum mX log(mX+eps) - sum mY log(mY+eps); marg scale 2^-22.
// ---------------------------------------------------------------------------
__global__ __launch_bounds__(256) void finalize_kernel(const float* __restrict__ accums,
                                                       const float* __restrict__ entPart,
                                                       const float* __restrict__ margX,
                                                       const float* __restrict__ margY,
                                                       float* __restrict__ out) {
    const int t = threadIdx.x;
    const int lane = t & 63, w = t >> 6;
    const float invN = 1.0f / 8192.0f;
    const float invM = 1.0f / 4194304.0f;   // 1/(512*8192) = 2^-22
    float sx = 0.f, sy = 0.f, se = 0.f;
    for (int c = t; c < CDIM; c += 256) {
        float mx = margX[c] * invM;
        float my = margY[c] * invM;
        sx += mx * __logf(mx + EPS);
        sy += my * __logf(my + EPS);
    }
    for (int c = t; c < 2048; c += 256) se += entPart[c];
    sx = wave_sum(sx); sy = wave_sum(sy); se = wave_sum(se);
    __shared__ float rx[4], ry[4], re[4];
    if (lane == 0) { rx[w] = sx; ry[w] = sy; re[w] = se; }
    __syncthreads();
    if (t == 0) {
        float SX = rx[0] + rx[1] + rx[2] + rx[3];
        float SY = ry[0] + ry[1] + ry[2] + ry[3];
        float SE = re[0] + re[1] + re[2] + re[3];
        out[0] = SE * invN;                 // mean entropy
        out[1] = accums[0] - SX - SY;       // MI
    }
}

// ---------------------------------------------------------------------------
// Workspace layout (bytes):
//   0          QX   fp8 [8192][4096]   33554432   (row-major probs x512)
//   33554432   QY   fp8 [8192][4096]   33554432
//   67108864   QXT  fp8 [4096][8192]   33554432   (transposed, GEMM operand)
//   100663296  QYT  fp8 [4096][8192]   33554432
//   134217728  margX f32[4096]            16384
//   134234112  margY f32[4096]            16384
//   134250496  accums f32[0]=S_jlogj        256
//   134250752  entPart f32[2048]           8192
// ---------------------------------------------------------------------------
extern "C" void kernel_launch(void* const* d_in, const int* in_sizes, int n_in,
                              void* d_out, int out_size, void* d_ws, size_t ws_size,
                              hipStream_t stream) {
    const float* X = (const float*)d_in[0];
    const float* Y = (const float*)d_in[1];
    char* ws = (char*)d_ws;
    unsigned char* QX  = (unsigned char*)ws;
    unsigned char* QY  = (unsigned char*)(ws + 33554432ll);
    unsigned char* QXT = (unsigned char*)(ws + 67108864ll);
    unsigned char* QYT = (unsigned char*)(ws + 100663296ll);
    float* margX = (float*)(ws + 134217728ll);
    float* margY = (float*)(ws + 134234112ll);
    float* accums = (float*)(ws + 134250496ll);
    float* entPart = (float*)(ws + 134250752ll);

    // zero margins + accumulators (ws is poisoned 0xAA before every launch)
    hipMemsetAsync(ws + 134217728ll, 0, 2 * 16384 + 256, stream);

    row_quant_kernel<<<dim3(2048, 2), 256, 0, stream>>>(X, Y, QX, QY, entPart);
    transpose_marg_kernel<<<dim3(CDIM / 128, NROWS / 128, 2), 256, 0, stream>>>(
        QX, QY, QXT, QYT, margX, margY);
    gemm_mi_kernel<<<dim3(CDIM / 256, CDIM / 256), 512, 0, stream>>>(QXT, QYT, &accums[0]);
    finalize_kernel<<<1, 256, 0, stream>>>(accums, entPart, margX, margY, (float*)d_out);
}